// Round 9
// baseline (132.323 us; speedup 1.0000x reference)
//
#include <hip/hip_runtime.h>
#include <math.h>

#define NTHREADS 256

typedef _Float16 v8h __attribute__((ext_vector_type(8)));
typedef float    v4f __attribute__((ext_vector_type(4)));

namespace {
constexpr int D   = 128;
constexpr int H   = 8;
constexpr int KNB = 48;
constexpr int KP1 = 49;
constexpr int NN  = 512;

// ---- workspace layout (bytes) ----
constexpr size_t WS_P    = 0;           // 8192*1024 f16 = 16,777,216  [a][c*8+h]
constexpr size_t WS_QKZ  = 16777216;    // 100*1024 f16  = 204,800
constexpr size_t WS_WVOT = 16982016;    // 128*1024 f16  = 262,144    [c'][d*8+h]
constexpr size_t WS_QZ   = 17244160;    // 100*128 f32   = 51,200
constexpr size_t WS_FWTP = 17295360;    // 4096 f16      = 8,192
constexpr size_t WS_EMBH = 17303552;    // 100*128 f16   = 25,600
constexpr size_t WS_NEED = 17329152;

constexpr float LOG_LO = -2.302585092994046f;  // ln(0.1)
constexpr float LOG_HI =  1.609437912434100f;  // ln(5.0)
constexpr float GWIDTH = (LOG_HI - LOG_LO) / 31.0f;
constexpr float GCOEFF = -0.5f / (GWIDTH * GWIDTH);
constexpr float PI_OVER_CUT = 3.14159265358979323846f / 5.0f;
}  // namespace

union H8U4 { _Float16 h[8]; uint4 u; };
union H4U2 { _Float16 h[4]; uint2 u; };

// ===========================================================================
// K0a: qz[zz][j] = emb[zz] @ Wq   (100x128 fp32) -- 50 blocks, 4-way ILP
// ===========================================================================
__global__ __launch_bounds__(NTHREADS) void k0a_qz(
    const float* __restrict__ embedding, const float* __restrict__ Wq,
    float* __restrict__ qz) {
  const int idx = blockIdx.x * NTHREADS + threadIdx.x;  // [0,12800)
  const int zz = idx >> 7, j = idx & 127;
  float a0 = 0.f, a1 = 0.f, a2 = 0.f, a3 = 0.f;
  for (int e = 0; e < 128; e += 4) {
    a0 = fmaf(embedding[zz * 128 + e + 0], Wq[(e + 0) * 128 + j], a0);
    a1 = fmaf(embedding[zz * 128 + e + 1], Wq[(e + 1) * 128 + j], a1);
    a2 = fmaf(embedding[zz * 128 + e + 2], Wq[(e + 2) * 128 + j], a2);
    a3 = fmaf(embedding[zz * 128 + e + 3], Wq[(e + 3) * 128 + j], a3);
  }
  qz[idx] = (a0 + a1) + (a2 + a3);
}

// ===========================================================================
// K0b: QKz (species-folded q.K, x0.25), WvoT2 (Wv.Wo fold, [c'][d*8+h]),
//      fWTP (filt_W B-frag order), embh (fp16 embedding) -- 964 blocks
// ===========================================================================
__global__ __launch_bounds__(NTHREADS) void k0b_prep(
    const float* __restrict__ filt_W, const float* __restrict__ Wk,
    const float* __restrict__ Wv, const float* __restrict__ Wo,
    const float* __restrict__ qz, const float* __restrict__ embedding,
    _Float16* __restrict__ QKz, _Float16* __restrict__ WvoT,
    _Float16* __restrict__ fWTP, _Float16* __restrict__ embh) {
  const int blk = blockIdx.x;
  const int tid = threadIdx.x;
  if (blk < 400) {
    const int idx = blk * NTHREADS + tid;     // [0,102400)
    const int zz = idx >> 10, hc = idx & 1023, h = hc >> 7, c = hc & 127;
    float acc = 0.0f;
#pragma unroll
    for (int e = 0; e < 16; ++e)
      acc = fmaf(qz[zz * 128 + h * 16 + e], Wk[c * 128 + h * 16 + e], acc);
    QKz[idx] = (_Float16)(acc * 0.25f);
  } else if (blk < 912) {
    // WvoT2[c'][d*8+h] = sum_cc Wv[d][h*16+cc] * Wo[h*16+cc][c']
    const int idx = (blk - 400) * NTHREADS + tid;  // [0,131072)
    const int cp = idx >> 10, kk = idx & 1023, d = kk >> 3, h = kk & 7;
    float acc = 0.0f;
#pragma unroll
    for (int cc = 0; cc < 16; ++cc)
      acc = fmaf(Wv[d * 128 + h * 16 + cc], Wo[(h * 16 + cc) * 128 + cp], acc);
    WvoT[idx] = (_Float16)acc;
  } else if (blk < 914) {
    const int i = (blk - 912) * NTHREADS + tid;    // [0,512) frag slots
    const int nt = i >> 6, quad = (i >> 4) & 3, col = i & 15;
    H8U4 pk;
#pragma unroll
    for (int j = 0; j < 8; ++j)
      pk.h[j] = (_Float16)filt_W[(quad * 8 + j) * 128 + nt * 16 + col];
    *(uint4*)&fWTP[i * 8] = pk.u;
  } else {
    const int idx = (blk - 914) * NTHREADS + tid;  // [0,12800)
    embh[idx] = (_Float16)embedding[idx];
  }
}

// ===========================================================================
// K2: per-atom attention core. Single TRANSPOSED kv layout kvT[c][t] with
// XOR-swizzled 8-half slots: phys_slot = (t>>3) ^ ((c>>3)&7).
//   Phase B writes: 8 x ds_write_b64 (4 consecutive t from C-layout regs)
//   Phase C reads:  32 x ds_read_u16 (the "wrong"-layout penalty, cheapest spot)
//   Phase E reads:  4 x ds_read_b128 (8 consecutive t per frag)
// LDS 24.4 KB -> 6 blocks/CU.
// ===========================================================================
namespace k2c {
constexpr int KVT_S = 72;   // halves per kvT row (9 slots of 8; slot 8 = pad)
constexpr int QK_S  = 136;  // 8 rows (col>=8 overreads -> garbage in dead D cols)
constexpr int ATH_S = 72;   // 9 rows; A-row addr clamped to min(col,8)
constexpr int SC_S  = 52;
constexpr int OFF_KVT = 0;                       // 128*72*2 = 18432
constexpr int OFF_QK  = 18432;                   // 8*136*2  = 2176
constexpr int OFF_ATH = 20608;                   // 9*72*2   = 1296
constexpr int OFF_SC  = 21904;                   // 8*52*4   = 1664
constexpr int OFF_LR  = 23568;                   // 208
constexpr int OFF_C   = 23776;
constexpr int OFF_MSK = 23984;
constexpr int OFF_ZJ  = 24192;
constexpr int SMEM    = 24400;                   // 6 blocks/CU
}  // namespace k2c

__global__ __launch_bounds__(NTHREADS, 6) void k2_attn(
    const float* __restrict__ positions, const int* __restrict__ z,
    const int* __restrict__ neighbors, const float* __restrict__ nmask,
    const _Float16* __restrict__ embh, const float* __restrict__ filt_b,
    const _Float16* __restrict__ fWTP, const _Float16* __restrict__ QKz,
    _Float16* __restrict__ P) {
  using namespace k2c;
  __shared__ __align__(16) char smem[SMEM];
  _Float16* s_kvT = reinterpret_cast<_Float16*>(smem + OFF_KVT);
  _Float16* s_qk  = reinterpret_cast<_Float16*>(smem + OFF_QK);
  _Float16* s_ath = reinterpret_cast<_Float16*>(smem + OFF_ATH);
  float*    s_sc  = reinterpret_cast<float*>(smem + OFF_SC);
  float*    s_lr  = reinterpret_cast<float*>(smem + OFF_LR);
  float*    s_C   = reinterpret_cast<float*>(smem + OFF_C);
  float*    s_msk = reinterpret_cast<float*>(smem + OFF_MSK);
  int*      s_zj  = reinterpret_cast<int*>(smem + OFF_ZJ);

  const int a   = blockIdx.x;
  const int b   = a >> 9;
  const int n   = a & (NN - 1);
  const int tid = threadIdx.x;
  const int w    = tid >> 6;
  const int lane = tid & 63;
  const int col  = lane & 15;
  const int quad = lane >> 4;

  const int zc = __builtin_amdgcn_readfirstlane(z[a]);

  // ---- Phase A: geometry | species-qk staging ----
  if (tid < KP1) {
    int j; float m;
    if (tid == 0) { j = n; m = 1.0f; }
    else { j = neighbors[a * KNB + tid - 1]; m = nmask[a * KNB + tid - 1]; }
    float r;
    if (tid == 0) r = 0.01f;
    else {
      const float dx = positions[(b * NN + j) * 3 + 0] - positions[a * 3 + 0];
      const float dy = positions[(b * NN + j) * 3 + 1] - positions[a * 3 + 1];
      const float dz = positions[(b * NN + j) * 3 + 2] - positions[a * 3 + 2];
      r = sqrtf(dx * dx + dy * dy + dz * dz + 1e-12f);
    }
    s_lr[tid]  = __logf(r);
    s_C[tid]   = (r < 5.0f) ? (0.5f * (__cosf(r * PI_OVER_CUT) + 1.0f)) : 0.0f;
    s_msk[tid] = m;
    s_zj[tid]  = z[b * NN + j];
  } else if (tid >= 128) {
    const int i = tid - 128;                     // [0,128): 2 KB coalesced
    const uint4 v = *(const uint4*)(QKz + (size_t)zc * 1024 + i * 8);
    const int h = i >> 4, dd = (i & 15) * 8;
    *(uint4*)&s_qk[h * QK_S + dd] = v;
  }
  __syncthreads();

  // ---- Phase B: P3 filter GEMM (MFMA) + kvT epilogue (b64 writes) ----
  {
    const int trow = 16 * w + col;
    const float lr = s_lr[trow < KP1 ? trow : KP1 - 1];
    v8h afrag;
#pragma unroll
    for (int j = 0; j < 8; ++j) {
      const int g = quad * 8 + j;
      const float dlt = lr - (LOG_LO + (float)g * GWIDTH);
      afrag[j] = (_Float16)__expf(GCOEFF * dlt * dlt);
    }
    v4f acc[8];
#pragma unroll
    for (int nt = 0; nt < 8; ++nt) {
      const v8h bfrag = *(const v8h*)(fWTP + (((nt * 4 + quad) * 16 + col) * 8));
      v4f zero = {0.0f, 0.0f, 0.0f, 0.0f};
      acc[nt] = __builtin_amdgcn_mfma_f32_16x16x32_f16(afrag, bfrag, zero, 0, 0, 0);
    }
    float bv[8];
#pragma unroll
    for (int nt = 0; nt < 8; ++nt) bv[nt] = filt_b[nt * 16 + col];
    // per-reg t metadata (cf=0 for invalid t -> exact zero kv rows 49..63)
    const int t0 = 16 * w + quad * 4;
    float cf4[4]; int zj4[4];
#pragma unroll
    for (int reg = 0; reg < 4; ++reg) {
      const int t = t0 + reg;
      const bool valid = t < KP1;
      cf4[reg] = valid ? s_C[t] : 0.0f;
      zj4[reg] = s_zj[valid ? t : KP1 - 1];
    }
    const int slot_log = 2 * w + (quad >> 1);    // t0 >> 3
    const int elem     = (quad & 1) * 4;         // t0 & 7
#pragma unroll
    for (int nt = 0; nt < 8; ++nt) {
      const int c = nt * 16 + col;
      const int phys = slot_log ^ ((c >> 3) & 7);
      H4U2 pk;
#pragma unroll
      for (int reg = 0; reg < 4; ++reg) {
        const float ev = (float)embh[(size_t)zj4[reg] * D + c];
        pk.h[reg] = (_Float16)((acc[nt][reg] + bv[nt]) * cf4[reg] * ev);
      }
      *(uint2*)&s_kvT[c * KVT_S + phys * 8 + elem] = pk.u;
    }
  }
  __syncthreads();

  // ---- Phase C: P6 scores via MFMA; A-frags gathered from kvT (u16) ----
  {
    v4f sacc = {0.0f, 0.0f, 0.0f, 0.0f};
    const int slot_log = 2 * w + (col >> 3);     // (16w+col) >> 3
    const int elem     = col & 7;
#pragma unroll
    for (int ks = 0; ks < 4; ++ks) {
      v8h afr;
#pragma unroll
      for (int j = 0; j < 8; ++j) {
        const int c = ks * 32 + quad * 8 + j;
        const int phys = slot_log ^ ((c >> 3) & 7);
        afr[j] = s_kvT[c * KVT_S + phys * 8 + elem];
      }
      const v8h bfr = *(const v8h*)&s_qk[col * QK_S + ks * 32 + quad * 8];
      sacc = __builtin_amdgcn_mfma_f32_16x16x32_f16(afr, bfr, sacc, 0, 0, 0);
    }
    const int h = col;
    if (h < H) {
#pragma unroll
      for (int reg = 0; reg < 4; ++reg) {
        const int t = 16 * w + quad * 4 + reg;
        if (t < KP1) {
          float sc = sacc[reg];
          if (s_msk[t] <= 0.0f) sc = -1e9f;
          s_sc[h * SC_S + t] = sc;
        }
      }
    }
  }
  __syncthreads();

  // ---- Phase D: softmax -> attn fp16 (t zero-padded to 64) ----
  if (tid < 64) {
    const int h  = tid >> 3;
    const int sl = tid & 7;
    float* row = &s_sc[h * SC_S];
    float m = -1e30f;
    for (int t = sl; t < KP1; t += 8) m = fmaxf(m, row[t]);
    m = fmaxf(m, __shfl_xor(m, 1));
    m = fmaxf(m, __shfl_xor(m, 2));
    m = fmaxf(m, __shfl_xor(m, 4));
    float s = 0.0f;
    float ev[7];
#pragma unroll
    for (int i = 0; i < 7; ++i) {
      const int t = sl + i * 8;
      const float e = (t < KP1) ? __expf(row[t] - m) : 0.0f;
      ev[i] = e;
      s += e;
    }
    s += __shfl_xor(s, 1);
    s += __shfl_xor(s, 2);
    s += __shfl_xor(s, 4);
    const float inv = 1.0f / s;
#pragma unroll
    for (int i = 0; i < 7; ++i) {
      const int t = sl + i * 8;
      if (t < KP1) s_ath[h * ATH_S + t] = (_Float16)(ev[i] * inv);
    }
  } else if (tid < 128) {
    const int i = tid - 64;
    for (int idx = i; idx < 8 * 15; idx += 64) {
      const int h = idx / 15;
      const int t = KP1 + idx % 15;
      s_ath[h * ATH_S + t] = (_Float16)0.0f;
    }
  }
  __syncthreads();

  // ---- Phase E: P8 p = attn @ kv via MFMA; B-frags b128 from kvT ----
  {
    const int arow = (col < 8) ? col : 8;        // clamp: garbage -> dead D rows
    const v8h a0 = *(const v8h*)&s_ath[arow * ATH_S + quad * 8];
    const v8h a1 = *(const v8h*)&s_ath[arow * ATH_S + 32 + quad * 8];
#pragma unroll
    for (int nti = 0; nti < 2; ++nti) {
      const int c = (2 * w + nti) * 16 + col;
      const int xr = (c >> 3) & 7;
      const v8h b0 = *(const v8h*)&s_kvT[c * KVT_S + ((quad)     ^ xr) * 8];
      const v8h b1 = *(const v8h*)&s_kvT[c * KVT_S + ((4 + quad) ^ xr) * 8];
      v4f pacc = {0.0f, 0.0f, 0.0f, 0.0f};
      pacc = __builtin_amdgcn_mfma_f32_16x16x32_f16(a0, b0, pacc, 0, 0, 0);
      pacc = __builtin_amdgcn_mfma_f32_16x16x32_f16(a1, b1, pacc, 0, 0, 0);
      if (quad < 2) {
        // h = quad*4+reg contiguous -> one b64 store, P layout [a][c*8+h]
        H4U2 pk;
#pragma unroll
        for (int reg = 0; reg < 4; ++reg) pk.h[reg] = (_Float16)pacc[reg];
        *(uint2*)(P + (size_t)a * 1024 + c * 8 + quad * 4) = pk.u;
      }
    }
  }
}

// ===========================================================================
// K3: MFMA GEMM  out(8192x128) = X + P(8192x1024) @ WvoT2^T(1024x128)
// 1024 blocks: 16 atoms x 64 cols each. k-order (d*8+h) on both operands.
// ===========================================================================
__global__ __launch_bounds__(NTHREADS) void k3_gemm(
    const int* __restrict__ z, const float* __restrict__ embedding,
    const _Float16* __restrict__ P, const _Float16* __restrict__ WvoT,
    float* __restrict__ out) {
  __shared__ __align__(16) _Float16 sA[16 * 136];    //  4352 B
  __shared__ __align__(16) _Float16 sB[64 * 136];    // 17408 B
  __shared__ int s_z[16];
  const int a0 = (blockIdx.x >> 1) * 16;
  const int n0 = (blockIdx.x & 1) * 64;
  const int tid = threadIdx.x;
  const int w    = tid >> 6;
  const int lane = tid & 63;
  const int col  = lane & 15;
  const int quad = lane >> 4;
  if (tid < 16) s_z[tid] = z[a0 + tid];

  v4f acc = (v4f){0.f, 0.f, 0.f, 0.f};

  for (int kc = 0; kc < 8; ++kc) {
    const int k0 = kc * 128;
    __syncthreads();
    // stage A: 16 x 128 halves (256 uint4, 1/thread)
    {
      const int ai = tid >> 4, sl = tid & 15;
      *(uint4*)&sA[ai * 136 + sl * 8] =
          *(const uint4*)(P + (size_t)(a0 + ai) * 1024 + k0 + sl * 8);
    }
    // stage B: 64 x 128 halves (1024 uint4, 4/thread)
#pragma unroll
    for (int it = 0; it < 4; ++it) {
      const int idx = it * NTHREADS + tid;
      const int cp = idx >> 4, sl = idx & 15;
      *(uint4*)&sB[cp * 136 + sl * 8] =
          *(const uint4*)(WvoT + (size_t)(n0 + cp) * 1024 + k0 + sl * 8);
    }
    __syncthreads();
#pragma unroll
    for (int ks = 0; ks < 4; ++ks) {
      const v8h af = *(const v8h*)&sA[col * 136 + ks * 32 + quad * 8];
      const v8h bf = *(const v8h*)&sB[(w * 16 + col) * 136 + ks * 32 + quad * 8];
      acc = __builtin_amdgcn_mfma_f32_16x16x32_f16(af, bf, acc, 0, 0, 0);
    }
  }
  // epilogue: out = x + acc
#pragma unroll
  for (int reg = 0; reg < 4; ++reg) {
    const int al = quad * 4 + reg;                    // local atom
    const int cp = n0 + w * 16 + col;
    out[(size_t)(a0 + al) * 128 + cp] =
        embedding[(size_t)s_z[al] * 128 + cp] + acc[reg];
  }
}

// ===========================================================================
// Fallback: round-4 monolithic kernel (used only if ws_size < WS_NEED)
// ===========================================================================
namespace mono {
constexpr int KV_S = 136, QK_S = 136, FWT_S = 40, ATH_S = 64, SC_S = 52, P_S = 132;
constexpr int OFF_KV = 0, OFF_FWT = 17408, OFF_P = 17408, OFF_AGG = 21632,
              OFF_QK = 27648, OFF_ATH = 32000, OFF_SC = 34048, OFF_Q = 35712,
              OFF_LR = 36224, OFF_C = 36432, OFF_MSK = 36640, OFF_ZJ = 36848,
              SMEM = 37056;
}  // namespace mono

__global__ __launch_bounds__(NTHREADS, 4) void tdt_mono(
    const float* __restrict__ positions, const int* __restrict__ z,
    const int* __restrict__ neighbors, const float* __restrict__ nmask,
    const float* __restrict__ embedding, const float* __restrict__ filt_W,
    const float* __restrict__ filt_b, const float* __restrict__ Wq,
    const float* __restrict__ Wk, const float* __restrict__ Wv,
    const float* __restrict__ Wo, float* __restrict__ out) {
  using namespace mono;
  __shared__ __align__(16) char smem[SMEM];
  _Float16* s_kvh = reinterpret_cast<_Float16*>(smem + OFF_KV);
  _Float16* s_fWT = reinterpret_cast<_Float16*>(smem + OFF_FWT);
  float*    s_p   = reinterpret_cast<float*>(smem + OFF_P);
  float*    s_agg = reinterpret_cast<float*>(smem + OFF_AGG);
  _Float16* s_qkh = reinterpret_cast<_Float16*>(smem + OFF_QK);
  _Float16* s_ath = reinterpret_cast<_Float16*>(smem + OFF_ATH);
  float*    s_sc  = reinterpret_cast<float*>(smem + OFF_SC);
  float*    s_q   = reinterpret_cast<float*>(smem + OFF_Q);
  float*    s_lr  = reinterpret_cast<float*>(smem + OFF_LR);
  float*    s_C   = reinterpret_cast<float*>(smem + OFF_C);
  float*    s_msk = reinterpret_cast<float*>(smem + OFF_MSK);
  int*      s_zj  = reinterpret_cast<int*>(smem + OFF_ZJ);
  const int a = blockIdx.x, b = a >> 9, n = a & (NN - 1), tid = threadIdx.x;
  const int w = tid >> 6, lane = tid & 63, col = lane & 15, quad = lane >> 4;
  const int zc = __builtin_amdgcn_readfirstlane(z[a]);
  if (tid < KP1) {
    int j; float m;
    if (tid == 0) { j = n; m = 1.0f; }
    else { j = neighbors[a * KNB + tid - 1]; m = nmask[a * KNB + tid - 1]; }
    float r;
    if (tid == 0) r = 0.01f;
    else {
      const float dx = positions[(b * NN + j) * 3 + 0] - positions[a * 3 + 0];
      const float dy = positions[(b * NN + j) * 3 + 1] - positions[a * 3 + 1];
      const float dz = positions[(b * NN + j) * 3 + 2] - positions[a * 3 + 2];
      r = sqrtf(dx * dx + dy * dy + dz * dz + 1e-12f);
    }
    s_lr[tid] = __logf(r);
    s_C[tid] = (r < 5.0f) ? (0.5f * (__cosf(r * PI_OVER_CUT) + 1.0f)) : 0.0f;
    s_msk[tid] = m;
    s_zj[tid] = z[b * NN + j];
  } else if (tid >= 64 && tid < 128) {
    const int i = tid - 64;
    for (int rep = 0; rep < 64; ++rep) {
      const int idx = rep * 64 + i;
      const int g = idx >> 7, c = idx & 127;
      s_fWT[c * FWT_S + g] = (_Float16)filt_W[idx];
    }
    unsigned* kz = reinterpret_cast<unsigned*>(s_kvh);
    for (int d0 = KP1 * (KV_S / 2) + i; d0 < 64 * (KV_S / 2); d0 += 64) kz[d0] = 0u;
  } else if (tid >= 128) {
    const int d = tid - 128;
    float acc = 0.0f;
    for (int e = 0; e < D; e += 4) {
      const float x0 = embedding[zc * D + e + 0];
      const float x1 = embedding[zc * D + e + 1];
      const float x2 = embedding[zc * D + e + 2];
      const float x3 = embedding[zc * D + e + 3];
      acc = fmaf(x0, Wq[(e + 0) * D + d], acc);
      acc = fmaf(x1, Wq[(e + 1) * D + d], acc);
      acc = fmaf(x2, Wq[(e + 2) * D + d], acc);
      acc = fmaf(x3, Wq[(e + 3) * D + d], acc);
    }
    s_q[d] = acc;
  }
  __syncthreads();
  {
    const int trow = 16 * w + col;
    const float lr = s_lr[trow < KP1 ? trow : KP1 - 1];
    v8h afrag;
#pragma unroll
    for (int j = 0; j < 8; ++j) {
      const int g = quad * 8 + j;
      const float dlt = lr - (LOG_LO + (float)g * GWIDTH);
      afrag[j] = (_Float16)__expf(GCOEFF * dlt * dlt);
    }
    v4f acc[8];
#pragma unroll
    for (int nt = 0; nt < 8; ++nt) {
      const v8h bfrag = *(const v8h*)&s_fWT[(nt * 16 + col) * FWT_S + quad * 8];
      v4f zero = {0.0f, 0.0f, 0.0f, 0.0f};
      acc[nt] = __builtin_amdgcn_mfma_f32_16x16x32_f16(afrag, bfrag, zero, 0, 0, 0);
    }
    float bv[8];
#pragma unroll
    for (int nt = 0; nt < 8; ++nt) bv[nt] = filt_b[nt * 16 + col];
#pragma unroll
    for (int reg = 0; reg < 4; ++reg) {
      const int t = 16 * w + quad * 4 + reg;
      const bool valid = t < KP1;
      float cf = 0.0f; int zj = 0;
      if (valid) { cf = s_C[t]; zj = s_zj[t]; }
      const float* erow = embedding + (size_t)zj * D;
#pragma unroll
      for (int nt = 0; nt < 8; ++nt) {
        const int c = nt * 16 + col;
        if (valid)
          s_kvh[t * KV_S + c] = (_Float16)((acc[nt][reg] + bv[nt]) * cf * erow[c]);
      }
    }
  }
  {
    const int h = tid & 7;
    const float4 q0 = *(const float4*)&s_q[h * 16 + 0];
    const float4 q1 = *(const float4*)&s_q[h * 16 + 4];
    const float4 q2 = *(const float4*)&s_q[h * 16 + 8];
    const float4 q3 = *(const float4*)&s_q[h * 16 + 12];
#pragma unroll
    for (int it = 0; it < 4; ++it) {
      const int d = ((it * NTHREADS + tid) >> 3);
      const float* wk = &Wk[d * D + h * 16];
      const float4 w0 = *(const float4*)&wk[0];
      const float4 w1 = *(const float4*)&wk[4];
      const float4 w2 = *(const float4*)&wk[8];
      const float4 w3 = *(const float4*)&wk[12];
      float s = w0.x * q0.x;
      s = fmaf(w0.y, q0.y, s); s = fmaf(w0.z, q0.z, s); s = fmaf(w0.w, q0.w, s);
      s = fmaf(w1.x, q1.x, s); s = fmaf(w1.y, q1.y, s);
      s = fmaf(w1.z, q1.z, s); s = fmaf(w1.w, q1.w, s);
      s = fmaf(w2.x, q2.x, s); s = fmaf(w2.y, q2.y, s);
      s = fmaf(w2.z, q2.z, s); s = fmaf(w2.w, q2.w, s);
      s = fmaf(w3.x, q3.x, s); s = fmaf(w3.y, q3.y, s);
      s = fmaf(w3.z, q3.z, s); s = fmaf(w3.w, q3.w, s);
      s_qkh[h * QK_S + d] = (_Float16)s;
    }
  }
  __syncthreads();
  {
    v4f sacc = {0.0f, 0.0f, 0.0f, 0.0f};
#pragma unroll
    for (int ks = 0; ks < 4; ++ks) {
      const v8h afr = *(const v8h*)&s_kvh[(16 * w + col) * KV_S + ks * 32 + quad * 8];
      const v8h bfr = *(const v8h*)&s_qkh[col * QK_S + ks * 32 + quad * 8];
      sacc = __builtin_amdgcn_mfma_f32_16x16x32_f16(afr, bfr, sacc, 0, 0, 0);
    }
    const int h = col;
    if (h < H) {
#pragma unroll
      for (int reg = 0; reg < 4; ++reg) {
        const int t = 16 * w + quad * 4 + reg;
        if (t < KP1) {
          float sc = sacc[reg] * 0.25f;
          if (s_msk[t] <= 0.0f) sc = -1e9f;
          s_sc[h * SC_S + t] = sc;
        }
      }
    }
  }
  __syncthreads();
  if (tid < 64) {
    const int h = tid >> 3, sl = tid & 7;
    float* row = &s_sc[h * SC_S];
    float m = -1e30f;
    for (int t = sl; t < KP1; t += 8) m = fmaxf(m, row[t]);
    m = fmaxf(m, __shfl_xor(m, 1));
    m = fmaxf(m, __shfl_xor(m, 2));
    m = fmaxf(m, __shfl_xor(m, 4));
    float s = 0.0f;
    float ev[7];
#pragma unroll
    for (int i = 0; i < 7; ++i) {
      const int t = sl + i * 8;
      const float e = (t < KP1) ? __expf(row[t] - m) : 0.0f;
      ev[i] = e; s += e;
    }
    s += __shfl_xor(s, 1);
    s += __shfl_xor(s, 2);
    s += __shfl_xor(s, 4);
    const float inv = 1.0f / s;
#pragma unroll
    for (int i = 0; i < 7; ++i) {
      const int t = sl + i * 8;
      if (t < KP1) s_ath[h * ATH_S + t] = (_Float16)(ev[i] * inv);
    }
  } else if (tid < 128) {
    const int i = tid - 64;
    for (int idx = i; idx < 8 * 15; idx += 64) {
      const int h = idx / 15, t = KP1 + idx % 15;
      s_ath[h * ATH_S + t] = (_Float16)0.0f;
    }
  }
  __syncthreads();
  {
    const v8h a0 = *(const v8h*)&s_ath[col * ATH_S + quad * 8];
    const v8h a1 = *(const v8h*)&s_ath[col * ATH_S + 32 + quad * 8];
#pragma unroll
    for (int nti = 0; nti < 2; ++nti) {
      const int c = (2 * w + nti) * 16 + col;
      v8h b0, b1;
#pragma unroll
      for (int j = 0; j < 8; ++j) {
        b0[j] = s_kvh[(quad * 8 + j) * KV_S + c];
        b1[j] = s_kvh[(32 + quad * 8 + j) * KV_S + c];
      }
      v4f pacc = {0.0f, 0.0f, 0.0f, 0.0f};
      pacc = __builtin_amdgcn_mfma_f32_16x16x32_f16(a0, b0, pacc, 0, 0, 0);
      pacc = __builtin_amdgcn_mfma_f32_16x16x32_f16(a1, b1, pacc, 0, 0, 0);
#pragma unroll
      for (int reg = 0; reg < 4; ++reg) {
        const int h = quad * 4 + reg;
        if (h < H) s_p[h * P_S + c] = pacc[reg];
      }
    }
  }
  __syncthreads();
  if (tid < 128) {
    const int c = tid;
    const float* pr = &s_p[(c >> 4) * P_S];
    float acc = 0.0f;
    for (int d = 0; d < D; d += 4) {
      const float4 p4 = *(const float4*)&pr[d];
      acc = fmaf(p4.x, Wv[(d + 0) * D + c], acc);
      acc = fmaf(p4.y, Wv[(d + 1) * D + c], acc);
      acc = fmaf(p4.z, Wv[(d + 2) * D + c], acc);
      acc = fmaf(p4.w, Wv[(d + 3) * D + c], acc);
    }
    s_agg[c] = acc;
  }
  __syncthreads();
  if (tid < 128) {
    const int c = tid;
    float acc = embedding[zc * D + c];
    for (int e = 0; e < D; e += 4) {
      const float4 g4 = *(const float4*)&s_agg[e];
      acc = fmaf(g4.x, Wo[(e + 0) * D + c], acc);
      acc = fmaf(g4.y, Wo[(e + 1) * D + c], acc);
      acc = fmaf(g4.z, Wo[(e + 2) * D + c], acc);
      acc = fmaf(g4.w, Wo[(e + 3) * D + c], acc);
    }
    out[a * D + c] = acc;
  }
}

// ===========================================================================
extern "C" void kernel_launch(void* const* d_in, const int* in_sizes, int n_in,
                              void* d_out, int out_size, void* d_ws, size_t ws_size,
                              hipStream_t stream) {
  const float* positions = (const float*)d_in[0];
  const int*   z         = (const int*)d_in[1];
  const int*   neighbors = (const int*)d_in[2];
  const float* nmask     = (const float*)d_in[3];
  const float* embedding = (const float*)d_in[4];
  const float* filt_W    = (const float*)d_in[5];
  const float* filt_b    = (const float*)d_in[6];
  const float* Wq        = (const float*)d_in[7];
  const float* Wk        = (const float*)d_in[8];
  const float* Wv        = (const float*)d_in[9];
  const float* Wo        = (const float*)d_in[10];
  float* out = (float*)d_out;
  const int natoms = in_sizes[1];  // 8192

  if (ws_size >= WS_NEED) {
    char* ws = (char*)d_ws;
    _Float16* P    = (_Float16*)(ws + WS_P);
    _Float16* QKz  = (_Float16*)(ws + WS_QKZ);
    _Float16* WvoT = (_Float16*)(ws + WS_WVOT);
    float*    qz   = (float*)(ws + WS_QZ);
    _Float16* fWTP = (_Float16*)(ws + WS_FWTP);
    _Float16* embh = (_Float16*)(ws + WS_EMBH);
    k0a_qz<<<50, NTHREADS, 0, stream>>>(embedding, Wq, qz);
    k0b_prep<<<964, NTHREADS, 0, stream>>>(filt_W, Wk, Wv, Wo, qz, embedding,
                                           QKz, WvoT, fWTP, embh);
    k2_attn<<<natoms, NTHREADS, 0, stream>>>(positions, z, neighbors, nmask,
                                             embh, filt_b, fWTP, QKz, P);
    k3_gemm<<<natoms / 16 * 2, NTHREADS, 0, stream>>>(z, embedding, P, WvoT, out);
  } else {
    tdt_mono<<<natoms, NTHREADS, 0, stream>>>(positions, z, neighbors, nmask,
                                              embedding, filt_W, filt_b,
                                              Wq, Wk, Wv, Wo, out);
  }
}

// Round 10
// 130.259 us; speedup vs baseline: 1.0158x; 1.0158x over previous
//
#include <hip/hip_runtime.h>
#include <math.h>

#define NTHREADS 256

typedef _Float16 v8h __attribute__((ext_vector_type(8)));
typedef _Float16 h2v __attribute__((ext_vector_type(2)));
typedef float    v4f __attribute__((ext_vector_type(4)));

namespace {
constexpr int D   = 128;
constexpr int H   = 8;
constexpr int KNB = 48;
constexpr int KP1 = 49;
constexpr int NN  = 512;

// ---- workspace layout (bytes) ----
constexpr size_t WS_P    = 0;           // 8192*1024 f16 = 16,777,216  [a][c*8+h]
constexpr size_t WS_QKZ  = 16777216;    // 100*1024 f16  = 204,800
constexpr size_t WS_WVOT = 16982016;    // 128*1024 f16  = 262,144    [c'][d*8+h]
constexpr size_t WS_QZ   = 17244160;    // 100*128 f32   = 51,200
constexpr size_t WS_FWTP = 17295360;    // 4096 f16      = 8,192
constexpr size_t WS_EMBH = 17303552;    // 100*128 f16   = 25,600
constexpr size_t WS_NEED = 17329152;

constexpr float LOG_LO = -2.302585092994046f;  // ln(0.1)
constexpr float LOG_HI =  1.609437912434100f;  // ln(5.0)
constexpr float GWIDTH = (LOG_HI - LOG_LO) / 31.0f;
constexpr float GCOEFF = -0.5f / (GWIDTH * GWIDTH);
constexpr float PI_OVER_CUT = 3.14159265358979323846f / 5.0f;
}  // namespace

union H8U4 { _Float16 h[8]; uint4 u; };
union H4U2 { _Float16 h[4]; uint2 u; };

// ===========================================================================
// K0a: qz[zz][j] = emb[zz] @ Wq   (100x128 fp32) -- 50 blocks, 4-way ILP
// ===========================================================================
__global__ __launch_bounds__(NTHREADS) void k0a_qz(
    const float* __restrict__ embedding, const float* __restrict__ Wq,
    float* __restrict__ qz) {
  const int idx = blockIdx.x * NTHREADS + threadIdx.x;  // [0,12800)
  const int zz = idx >> 7, j = idx & 127;
  float a0 = 0.f, a1 = 0.f, a2 = 0.f, a3 = 0.f;
  for (int e = 0; e < 128; e += 4) {
    a0 = fmaf(embedding[zz * 128 + e + 0], Wq[(e + 0) * 128 + j], a0);
    a1 = fmaf(embedding[zz * 128 + e + 1], Wq[(e + 1) * 128 + j], a1);
    a2 = fmaf(embedding[zz * 128 + e + 2], Wq[(e + 2) * 128 + j], a2);
    a3 = fmaf(embedding[zz * 128 + e + 3], Wq[(e + 3) * 128 + j], a3);
  }
  qz[idx] = (a0 + a1) + (a2 + a3);
}

// ===========================================================================
// K0b: QKz (species-folded q.K, x0.25), WvoT2 (Wv.Wo fold, [c'][d*8+h]),
//      fWTP (filt_W B-frag order), embh (fp16 embedding) -- 964 blocks
// ===========================================================================
__global__ __launch_bounds__(NTHREADS) void k0b_prep(
    const float* __restrict__ filt_W, const float* __restrict__ Wk,
    const float* __restrict__ Wv, const float* __restrict__ Wo,
    const float* __restrict__ qz, const float* __restrict__ embedding,
    _Float16* __restrict__ QKz, _Float16* __restrict__ WvoT,
    _Float16* __restrict__ fWTP, _Float16* __restrict__ embh) {
  const int blk = blockIdx.x;
  const int tid = threadIdx.x;
  if (blk < 400) {
    const int idx = blk * NTHREADS + tid;     // [0,102400)
    const int zz = idx >> 10, hc = idx & 1023, h = hc >> 7, c = hc & 127;
    float acc = 0.0f;
#pragma unroll
    for (int e = 0; e < 16; ++e)
      acc = fmaf(qz[zz * 128 + h * 16 + e], Wk[c * 128 + h * 16 + e], acc);
    QKz[idx] = (_Float16)(acc * 0.25f);
  } else if (blk < 912) {
    // WvoT2[c'][d*8+h] = sum_cc Wv[d][h*16+cc] * Wo[h*16+cc][c']
    const int idx = (blk - 400) * NTHREADS + tid;  // [0,131072)
    const int cp = idx >> 10, kk = idx & 1023, d = kk >> 3, h = kk & 7;
    float acc = 0.0f;
#pragma unroll
    for (int cc = 0; cc < 16; ++cc)
      acc = fmaf(Wv[d * 128 + h * 16 + cc], Wo[(h * 16 + cc) * 128 + cp], acc);
    WvoT[idx] = (_Float16)acc;
  } else if (blk < 914) {
    const int i = (blk - 912) * NTHREADS + tid;    // [0,512) frag slots
    const int nt = i >> 6, quad = (i >> 4) & 3, col = i & 15;
    H8U4 pk;
#pragma unroll
    for (int j = 0; j < 8; ++j)
      pk.h[j] = (_Float16)filt_W[(quad * 8 + j) * 128 + nt * 16 + col];
    *(uint4*)&fWTP[i * 8] = pk.u;
  } else {
    const int idx = (blk - 914) * NTHREADS + tid;  // [0,12800)
    embh[idx] = (_Float16)embedding[idx];
  }
}

// ===========================================================================
// K2: per-atom attention core. Transposed kv layout kvT[c][t], XOR slots.
// LDS diet: fp16 scores + s_ath aliased onto dead s_qk -> 22272 B ->
// 7 blocks/CU. Packed-fp16 epilogue in Phase B.
// ===========================================================================
namespace k2c {
constexpr int KVT_S = 72;   // halves per kvT row (9 slots of 8; slot 8 = pad)
constexpr int QK_S  = 136;  // 8 rows (col>=8 overreads -> garbage in dead D cols)
constexpr int ATH_S = 72;   // 9 rows; aliased onto QK region (dead after Phase C)
constexpr int SC_S  = 52;   // halves per score row (fp16 scores)
constexpr int OFF_KVT = 0;                       // 128*72*2 = 18432
constexpr int OFF_QK  = 18432;                   // 8*136*2  = 2176
constexpr int OFF_ATH = OFF_QK;                  // alias: 9*72*2 = 1296 <= 2176
constexpr int OFF_SC  = 20608;                   // 8*52*2   = 832
constexpr int OFF_LR  = 21440;                   // 208
constexpr int OFF_C   = 21648;                   // 208
constexpr int OFF_MSK = 21856;                   // 208
constexpr int OFF_ZJ  = 22064;                   // 208
constexpr int SMEM    = 22272;                   // 7 blocks/CU (7*22272=155904)
}  // namespace k2c

__global__ __launch_bounds__(NTHREADS, 7) void k2_attn(
    const float* __restrict__ positions, const int* __restrict__ z,
    const int* __restrict__ neighbors, const float* __restrict__ nmask,
    const _Float16* __restrict__ embh, const float* __restrict__ filt_b,
    const _Float16* __restrict__ fWTP, const _Float16* __restrict__ QKz,
    _Float16* __restrict__ P) {
  using namespace k2c;
  __shared__ __align__(16) char smem[SMEM];
  _Float16* s_kvT = reinterpret_cast<_Float16*>(smem + OFF_KVT);
  _Float16* s_qk  = reinterpret_cast<_Float16*>(smem + OFF_QK);
  _Float16* s_ath = reinterpret_cast<_Float16*>(smem + OFF_ATH);
  _Float16* s_sc  = reinterpret_cast<_Float16*>(smem + OFF_SC);
  float*    s_lr  = reinterpret_cast<float*>(smem + OFF_LR);
  float*    s_C   = reinterpret_cast<float*>(smem + OFF_C);
  float*    s_msk = reinterpret_cast<float*>(smem + OFF_MSK);
  int*      s_zj  = reinterpret_cast<int*>(smem + OFF_ZJ);

  const int a   = blockIdx.x;
  const int b   = a >> 9;
  const int n   = a & (NN - 1);
  const int tid = threadIdx.x;
  const int w    = tid >> 6;
  const int lane = tid & 63;
  const int col  = lane & 15;
  const int quad = lane >> 4;

  const int zc = __builtin_amdgcn_readfirstlane(z[a]);

  // ---- Phase A: geometry | species-qk staging ----
  if (tid < KP1) {
    int j; float m;
    if (tid == 0) { j = n; m = 1.0f; }
    else { j = neighbors[a * KNB + tid - 1]; m = nmask[a * KNB + tid - 1]; }
    float r;
    if (tid == 0) r = 0.01f;
    else {
      const float dx = positions[(b * NN + j) * 3 + 0] - positions[a * 3 + 0];
      const float dy = positions[(b * NN + j) * 3 + 1] - positions[a * 3 + 1];
      const float dz = positions[(b * NN + j) * 3 + 2] - positions[a * 3 + 2];
      r = sqrtf(dx * dx + dy * dy + dz * dz + 1e-12f);
    }
    s_lr[tid]  = __logf(r);
    s_C[tid]   = (r < 5.0f) ? (0.5f * (__cosf(r * PI_OVER_CUT) + 1.0f)) : 0.0f;
    s_msk[tid] = m;
    s_zj[tid]  = z[b * NN + j];
  } else if (tid >= 128) {
    const int i = tid - 128;                     // [0,128): 2 KB coalesced
    const uint4 v = *(const uint4*)(QKz + (size_t)zc * 1024 + i * 8);
    const int h = i >> 4, dd = (i & 15) * 8;
    *(uint4*)&s_qk[h * QK_S + dd] = v;
  }
  __syncthreads();

  // ---- Phase B: P3 filter GEMM (MFMA) + packed-fp16 kvT epilogue ----
  {
    const int trow = 16 * w + col;
    const float lr = s_lr[trow < KP1 ? trow : KP1 - 1];
    v8h afrag;
#pragma unroll
    for (int j = 0; j < 8; ++j) {
      const int g = quad * 8 + j;
      const float dlt = lr - (LOG_LO + (float)g * GWIDTH);
      afrag[j] = (_Float16)__expf(GCOEFF * dlt * dlt);
    }
    v4f acc[8];
#pragma unroll
    for (int nt = 0; nt < 8; ++nt) {
      const v8h bfrag = *(const v8h*)(fWTP + (((nt * 4 + quad) * 16 + col) * 8));
      v4f zero = {0.0f, 0.0f, 0.0f, 0.0f};
      acc[nt] = __builtin_amdgcn_mfma_f32_16x16x32_f16(afrag, bfrag, zero, 0, 0, 0);
    }
    float bv[8];
#pragma unroll
    for (int nt = 0; nt < 8; ++nt) bv[nt] = filt_b[nt * 16 + col];
    // per-reg t metadata (cf=0 for invalid t -> exact zero kv rows 49..63)
    const int t0 = 16 * w + quad * 4;
    float cf4[4]; int zj4[4];
#pragma unroll
    for (int reg = 0; reg < 4; ++reg) {
      const int t = t0 + reg;
      const bool valid = t < KP1;
      cf4[reg] = valid ? s_C[t] : 0.0f;
      zj4[reg] = s_zj[valid ? t : KP1 - 1];
    }
    const h2v cf01 = {(_Float16)cf4[0], (_Float16)cf4[1]};
    const h2v cf23 = {(_Float16)cf4[2], (_Float16)cf4[3]};
    const int slot_log = 2 * w + (quad >> 1);    // t0 >> 3
    const int elem     = (quad & 1) * 4;         // t0 & 7
#pragma unroll
    for (int nt = 0; nt < 8; ++nt) {
      const int c = nt * 16 + col;
      const _Float16 bvh = (_Float16)bv[nt];
      const h2v cfbv01 = cf01 * bvh;             // v_pk_mul_f16
      const h2v cfbv23 = cf23 * bvh;
      const h2v a01 = {(_Float16)acc[nt][0], (_Float16)acc[nt][1]};
      const h2v a23 = {(_Float16)acc[nt][2], (_Float16)acc[nt][3]};
      const h2v ev01 = {embh[(size_t)zj4[0] * D + c],
                        embh[(size_t)zj4[1] * D + c]};
      const h2v ev23 = {embh[(size_t)zj4[2] * D + c],
                        embh[(size_t)zj4[3] * D + c]};
      const h2v kv01 = (a01 * cf01 + cfbv01) * ev01;
      const h2v kv23 = (a23 * cf23 + cfbv23) * ev23;
      uint2 u;
      __builtin_memcpy(&u.x, &kv01, 4);
      __builtin_memcpy(&u.y, &kv23, 4);
      const int phys = slot_log ^ ((c >> 3) & 7);
      *(uint2*)&s_kvT[c * KVT_S + phys * 8 + elem] = u;
    }
  }
  __syncthreads();

  // ---- Phase C: P6 scores via MFMA; A-frags gathered from kvT (u16) ----
  {
    v4f sacc = {0.0f, 0.0f, 0.0f, 0.0f};
    const int slot_log = 2 * w + (col >> 3);     // (16w+col) >> 3
    const int elem     = col & 7;
#pragma unroll
    for (int ks = 0; ks < 4; ++ks) {
      v8h afr;
#pragma unroll
      for (int j = 0; j < 8; ++j) {
        const int c = ks * 32 + quad * 8 + j;
        const int phys = slot_log ^ ((c >> 3) & 7);
        afr[j] = s_kvT[c * KVT_S + phys * 8 + elem];
      }
      const v8h bfr = *(const v8h*)&s_qk[col * QK_S + ks * 32 + quad * 8];
      sacc = __builtin_amdgcn_mfma_f32_16x16x32_f16(afr, bfr, sacc, 0, 0, 0);
    }
    const int h = col;
    if (h < H) {
#pragma unroll
      for (int reg = 0; reg < 4; ++reg) {
        const int t = 16 * w + quad * 4 + reg;
        if (t < KP1) {
          // fp16 score; masked = -60000 (exp-safe, fp16-representable)
          s_sc[h * SC_S + t] = (s_msk[t] > 0.0f) ? (_Float16)sacc[reg]
                                                 : (_Float16)(-60000.0f);
        }
      }
    }
  }
  __syncthreads();

  // ---- Phase D: softmax -> attn fp16 into s_ath (aliases dead s_qk) ----
  if (tid < 64) {
    const int h  = tid >> 3;
    const int sl = tid & 7;
    const _Float16* row = &s_sc[h * SC_S];
    float m = -1e30f;
    for (int t = sl; t < KP1; t += 8) m = fmaxf(m, (float)row[t]);
    m = fmaxf(m, __shfl_xor(m, 1));
    m = fmaxf(m, __shfl_xor(m, 2));
    m = fmaxf(m, __shfl_xor(m, 4));
    float s = 0.0f;
    float ev[7];
#pragma unroll
    for (int i = 0; i < 7; ++i) {
      const int t = sl + i * 8;
      const float e = (t < KP1) ? __expf((float)row[t] - m) : 0.0f;
      ev[i] = e;
      s += e;
    }
    s += __shfl_xor(s, 1);
    s += __shfl_xor(s, 2);
    s += __shfl_xor(s, 4);
    const float inv = 1.0f / s;
#pragma unroll
    for (int i = 0; i < 7; ++i) {
      const int t = sl + i * 8;
      if (t < KP1) s_ath[h * ATH_S + t] = (_Float16)(ev[i] * inv);
    }
  } else if (tid < 128) {
    const int i = tid - 64;
    for (int idx = i; idx < 8 * 15; idx += 64) {
      const int h = idx / 15;
      const int t = KP1 + idx % 15;
      s_ath[h * ATH_S + t] = (_Float16)0.0f;
    }
  }
  __syncthreads();

  // ---- Phase E: P8 p = attn @ kv via MFMA; B-frags b128 from kvT ----
  {
    const int arow = (col < 8) ? col : 8;        // clamp: garbage -> dead D rows
    const v8h a0 = *(const v8h*)&s_ath[arow * ATH_S + quad * 8];
    const v8h a1 = *(const v8h*)&s_ath[arow * ATH_S + 32 + quad * 8];
#pragma unroll
    for (int nti = 0; nti < 2; ++nti) {
      const int c = (2 * w + nti) * 16 + col;
      const int xr = (c >> 3) & 7;
      const v8h b0 = *(const v8h*)&s_kvT[c * KVT_S + ((quad)     ^ xr) * 8];
      const v8h b1 = *(const v8h*)&s_kvT[c * KVT_S + ((4 + quad) ^ xr) * 8];
      v4f pacc = {0.0f, 0.0f, 0.0f, 0.0f};
      pacc = __builtin_amdgcn_mfma_f32_16x16x32_f16(a0, b0, pacc, 0, 0, 0);
      pacc = __builtin_amdgcn_mfma_f32_16x16x32_f16(a1, b1, pacc, 0, 0, 0);
      if (quad < 2) {
        // h = quad*4+reg contiguous -> one b64 store, P layout [a][c*8+h]
        H4U2 pk;
#pragma unroll
        for (int reg = 0; reg < 4; ++reg) pk.h[reg] = (_Float16)pacc[reg];
        *(uint2*)(P + (size_t)a * 1024 + c * 8 + quad * 4) = pk.u;
      }
    }
  }
}

// ===========================================================================
// K3: MFMA GEMM  out(8192x128) = X + P(8192x1024) @ WvoT2^T(1024x128)
// 1024 blocks: 16 atoms x 64 cols each. k-order (d*8+h) on both operands.
// ===========================================================================
__global__ __launch_bounds__(NTHREADS) void k3_gemm(
    const int* __restrict__ z, const float* __restrict__ embedding,
    const _Float16* __restrict__ P, const _Float16* __restrict__ WvoT,
    float* __restrict__ out) {
  __shared__ __align__(16) _Float16 sA[16 * 136];    //  4352 B
  __shared__ __align__(16) _Float16 sB[64 * 136];    // 17408 B
  __shared__ int s_z[16];
  const int a0 = (blockIdx.x >> 1) * 16;
  const int n0 = (blockIdx.x & 1) * 64;
  const int tid = threadIdx.x;
  const int w    = tid >> 6;
  const int lane = tid & 63;
  const int col  = lane & 15;
  const int quad = lane >> 4;
  if (tid < 16) s_z[tid] = z[a0 + tid];

  v4f acc = (v4f){0.f, 0.f, 0.f, 0.f};

  for (int kc = 0; kc < 8; ++kc) {
    const int k0 = kc * 128;
    __syncthreads();
    // stage A: 16 x 128 halves (256 uint4, 1/thread)
    {
      const int ai = tid >> 4, sl = tid & 15;
      *(uint4*)&sA[ai * 136 + sl * 8] =
          *(const uint4*)(P + (size_t)(a0 + ai) * 1024 + k0 + sl * 8);
    }
    // stage B: 64 x 128 halves (1024 uint4, 4/thread)
#pragma unroll
    for (int it = 0; it < 4; ++it) {
      const int idx = it * NTHREADS + tid;
      const int cp = idx >> 4, sl = idx & 15;
      *(uint4*)&sB[cp * 136 + sl * 8] =
          *(const uint4*)(WvoT + (size_t)(n0 + cp) * 1024 + k0 + sl * 8);
    }
    __syncthreads();
#pragma unroll
    for (int ks = 0; ks < 4; ++ks) {
      const v8h af = *(const v8h*)&sA[col * 136 + ks * 32 + quad * 8];
      const v8h bf = *(const v8h*)&sB[(w * 16 + col) * 136 + ks * 32 + quad * 8];
      acc = __builtin_amdgcn_mfma_f32_16x16x32_f16(af, bf, acc, 0, 0, 0);
    }
  }
  // epilogue: out = x + acc
#pragma unroll
  for (int reg = 0; reg < 4; ++reg) {
    const int al = quad * 4 + reg;                    // local atom
    const int cp = n0 + w * 16 + col;
    out[(size_t)(a0 + al) * 128 + cp] =
        embedding[(size_t)s_z[al] * 128 + cp] + acc[reg];
  }
}

// ===========================================================================
// Fallback: round-4 monolithic kernel (used only if ws_size < WS_NEED)
// ===========================================================================
namespace mono {
constexpr int KV_S = 136, QK_S = 136, FWT_S = 40, ATH_S = 64, SC_S = 52, P_S = 132;
constexpr int OFF_KV = 0, OFF_FWT = 17408, OFF_P = 17408, OFF_AGG = 21632,
              OFF_QK = 27648, OFF_ATH = 32000, OFF_SC = 34048, OFF_Q = 35712,
              OFF_LR = 36224, OFF_C = 36432, OFF_MSK = 36640, OFF_ZJ = 36848,
              SMEM = 37056;
}  // namespace mono

__global__ __launch_bounds__(NTHREADS, 4) void tdt_mono(
    const float* __restrict__ positions, const int* __restrict__ z,
    const int* __restrict__ neighbors, const float* __restrict__ nmask,
    const float* __restrict__ embedding, const float* __restrict__ filt_W,
    const float* __restrict__ filt_b, const float* __restrict__ Wq,
    const float* __restrict__ Wk, const float* __restrict__ Wv,
    const float* __restrict__ Wo, float* __restrict__ out) {
  using namespace mono;
  __shared__ __align__(16) char smem[SMEM];
  _Float16* s_kvh = reinterpret_cast<_Float16*>(smem + OFF_KV);
  _Float16* s_fWT = reinterpret_cast<_Float16*>(smem + OFF_FWT);
  float*    s_p   = reinterpret_cast<float*>(smem + OFF_P);
  float*    s_agg = reinterpret_cast<float*>(smem + OFF_AGG);
  _Float16* s_qkh = reinterpret_cast<_Float16*>(smem + OFF_QK);
  _Float16* s_ath = reinterpret_cast<_Float16*>(smem + OFF_ATH);
  float*    s_sc  = reinterpret_cast<float*>(smem + OFF_SC);
  float*    s_q   = reinterpret_cast<float*>(smem + OFF_Q);
  float*    s_lr  = reinterpret_cast<float*>(smem + OFF_LR);
  float*    s_C   = reinterpret_cast<float*>(smem + OFF_C);
  float*    s_msk = reinterpret_cast<float*>(smem + OFF_MSK);
  int*      s_zj  = reinterpret_cast<int*>(smem + OFF_ZJ);
  const int a = blockIdx.x, b = a >> 9, n = a & (NN - 1), tid = threadIdx.x;
  const int w = tid >> 6, lane = tid & 63, col = lane & 15, quad = lane >> 4;
  const int zc = __builtin_amdgcn_readfirstlane(z[a]);
  if (tid < KP1) {
    int j; float m;
    if (tid == 0) { j = n; m = 1.0f; }
    else { j = neighbors[a * KNB + tid - 1]; m = nmask[a * KNB + tid - 1]; }
    float r;
    if (tid == 0) r = 0.01f;
    else {
      const float dx = positions[(b * NN + j) * 3 + 0] - positions[a * 3 + 0];
      const float dy = positions[(b * NN + j) * 3 + 1] - positions[a * 3 + 1];
      const float dz = positions[(b * NN + j) * 3 + 2] - positions[a * 3 + 2];
      r = sqrtf(dx * dx + dy * dy + dz * dz + 1e-12f);
    }
    s_lr[tid] = __logf(r);
    s_C[tid] = (r < 5.0f) ? (0.5f * (__cosf(r * PI_OVER_CUT) + 1.0f)) : 0.0f;
    s_msk[tid] = m;
    s_zj[tid] = z[b * NN + j];
  } else if (tid >= 64 && tid < 128) {
    const int i = tid - 64;
    for (int rep = 0; rep < 64; ++rep) {
      const int idx = rep * 64 + i;
      const int g = idx >> 7, c = idx & 127;
      s_fWT[c * FWT_S + g] = (_Float16)filt_W[idx];
    }
    unsigned* kz = reinterpret_cast<unsigned*>(s_kvh);
    for (int d0 = KP1 * (KV_S / 2) + i; d0 < 64 * (KV_S / 2); d0 += 64) kz[d0] = 0u;
  } else if (tid >= 128) {
    const int d = tid - 128;
    float acc = 0.0f;
    for (int e = 0; e < D; e += 4) {
      const float x0 = embedding[zc * D + e + 0];
      const float x1 = embedding[zc * D + e + 1];
      const float x2 = embedding[zc * D + e + 2];
      const float x3 = embedding[zc * D + e + 3];
      acc = fmaf(x0, Wq[(e + 0) * D + d], acc);
      acc = fmaf(x1, Wq[(e + 1) * D + d], acc);
      acc = fmaf(x2, Wq[(e + 2) * D + d], acc);
      acc = fmaf(x3, Wq[(e + 3) * D + d], acc);
    }
    s_q[d] = acc;
  }
  __syncthreads();
  {
    const int trow = 16 * w + col;
    const float lr = s_lr[trow < KP1 ? trow : KP1 - 1];
    v8h afrag;
#pragma unroll
    for (int j = 0; j < 8; ++j) {
      const int g = quad * 8 + j;
      const float dlt = lr - (LOG_LO + (float)g * GWIDTH);
      afrag[j] = (_Float16)__expf(GCOEFF * dlt * dlt);
    }
    v4f acc[8];
#pragma unroll
    for (int nt = 0; nt < 8; ++nt) {
      const v8h bfrag = *(const v8h*)&s_fWT[(nt * 16 + col) * FWT_S + quad * 8];
      v4f zero = {0.0f, 0.0f, 0.0f, 0.0f};
      acc[nt] = __builtin_amdgcn_mfma_f32_16x16x32_f16(afrag, bfrag, zero, 0, 0, 0);
    }
    float bv[8];
#pragma unroll
    for (int nt = 0; nt < 8; ++nt) bv[nt] = filt_b[nt * 16 + col];
#pragma unroll
    for (int reg = 0; reg < 4; ++reg) {
      const int t = 16 * w + quad * 4 + reg;
      const bool valid = t < KP1;
      float cf = 0.0f; int zj = 0;
      if (valid) { cf = s_C[t]; zj = s_zj[t]; }
      const float* erow = embedding + (size_t)zj * D;
#pragma unroll
      for (int nt = 0; nt < 8; ++nt) {
        const int c = nt * 16 + col;
        if (valid)
          s_kvh[t * KV_S + c] = (_Float16)((acc[nt][reg] + bv[nt]) * cf * erow[c]);
      }
    }
  }
  {
    const int h = tid & 7;
    const float4 q0 = *(const float4*)&s_q[h * 16 + 0];
    const float4 q1 = *(const float4*)&s_q[h * 16 + 4];
    const float4 q2 = *(const float4*)&s_q[h * 16 + 8];
    const float4 q3 = *(const float4*)&s_q[h * 16 + 12];
#pragma unroll
    for (int it = 0; it < 4; ++it) {
      const int d = ((it * NTHREADS + tid) >> 3);
      const float* wk = &Wk[d * D + h * 16];
      const float4 w0 = *(const float4*)&wk[0];
      const float4 w1 = *(const float4*)&wk[4];
      const float4 w2 = *(const float4*)&wk[8];
      const float4 w3 = *(const float4*)&wk[12];
      float s = w0.x * q0.x;
      s = fmaf(w0.y, q0.y, s); s = fmaf(w0.z, q0.z, s); s = fmaf(w0.w, q0.w, s);
      s = fmaf(w1.x, q1.x, s); s = fmaf(w1.y, q1.y, s);
      s = fmaf(w1.z, q1.z, s); s = fmaf(w1.w, q1.w, s);
      s = fmaf(w2.x, q2.x, s); s = fmaf(w2.y, q2.y, s);
      s = fmaf(w2.z, q2.z, s); s = fmaf(w2.w, q2.w, s);
      s = fmaf(w3.x, q3.x, s); s = fmaf(w3.y, q3.y, s);
      s = fmaf(w3.z, q3.z, s); s = fmaf(w3.w, q3.w, s);
      s_qkh[h * QK_S + d] = (_Float16)s;
    }
  }
  __syncthreads();
  {
    v4f sacc = {0.0f, 0.0f, 0.0f, 0.0f};
#pragma unroll
    for (int ks = 0; ks < 4; ++ks) {
      const v8h afr = *(const v8h*)&s_kvh[(16 * w + col) * KV_S + ks * 32 + quad * 8];
      const v8h bfr = *(const v8h*)&s_qkh[col * QK_S + ks * 32 + quad * 8];
      sacc = __builtin_amdgcn_mfma_f32_16x16x32_f16(afr, bfr, sacc, 0, 0, 0);
    }
    const int h = col;
    if (h < H) {
#pragma unroll
      for (int reg = 0; reg < 4; ++reg) {
        const int t = 16 * w + quad * 4 + reg;
        if (t < KP1) {
          float sc = sacc[reg] * 0.25f;
          if (s_msk[t] <= 0.0f) sc = -1e9f;
          s_sc[h * SC_S + t] = sc;
        }
      }
    }
  }
  __syncthreads();
  if (tid < 64) {
    const int h = tid >> 3, sl = tid & 7;
    float* row = &s_sc[h * SC_S];
    float m = -1e30f;
    for (int t = sl; t < KP1; t += 8) m = fmaxf(m, row[t]);
    m = fmaxf(m, __shfl_xor(m, 1));
    m = fmaxf(m, __shfl_xor(m, 2));
    m = fmaxf(m, __shfl_xor(m, 4));
    float s = 0.0f;
    float ev[7];
#pragma unroll
    for (int i = 0; i < 7; ++i) {
      const int t = sl + i * 8;
      const float e = (t < KP1) ? __expf(row[t] - m) : 0.0f;
      ev[i] = e; s += e;
    }
    s += __shfl_xor(s, 1);
    s += __shfl_xor(s, 2);
    s += __shfl_xor(s, 4);
    const float inv = 1.0f / s;
#pragma unroll
    for (int i = 0; i < 7; ++i) {
      const int t = sl + i * 8;
      if (t < KP1) s_ath[h * ATH_S + t] = (_Float16)(ev[i] * inv);
    }
  } else if (tid < 128) {
    const int i = tid - 64;
    for (int idx = i; idx < 8 * 15; idx += 64) {
      const int h = idx / 15, t = KP1 + idx % 15;
      s_ath[h * ATH_S + t] = (_Float16)0.0f;
    }
  }
  __syncthreads();
  {
    const v8h a0 = *(const v8h*)&s_ath[col * ATH_S + quad * 8];
    const v8h a1 = *(const v8h*)&s_ath[col * ATH_S + 32 + quad * 8];
#pragma unroll
    for (int nti = 0; nti < 2; ++nti) {
      const int c = (2 * w + nti) * 16 + col;
      v8h b0, b1;
#pragma unroll
      for (int j = 0; j < 8; ++j) {
        b0[j] = s_kvh[(quad * 8 + j) * KV_S + c];
        b1[j] = s_kvh[(32 + quad * 8 + j) * KV_S + c];
      }
      v4f pacc = {0.0f, 0.0f, 0.0f, 0.0f};
      pacc = __builtin_amdgcn_mfma_f32_16x16x32_f16(a0, b0, pacc, 0, 0, 0);
      pacc = __builtin_amdgcn_mfma_f32_16x16x32_f16(a1, b1, pacc, 0, 0, 0);
#pragma unroll
      for (int reg = 0; reg < 4; ++reg) {
        const int h = quad * 4 + reg;
        if (h < H) s_p[h * P_S + c] = pacc[reg];
      }
    }
  }
  __syncthreads();
  if (tid < 128) {
    const int c = tid;
    const float* pr = &s_p[(c >> 4) * P_S];
    float acc = 0.0f;
    for (int d = 0; d < D; d += 4) {
      const float4 p4 = *(const float4*)&pr[d];
      acc = fmaf(p4.x, Wv[(d + 0) * D + c], acc);
      acc = fmaf(p4.y, Wv[(d + 1) * D + c], acc);
      acc = fmaf(p4.z, Wv[(d + 2) * D + c], acc);
      acc = fmaf(p4.w, Wv[(d + 3) * D + c], acc);
    }
    s_agg[c] = acc;
  }
  __syncthreads();
  if (tid < 128) {
    const int c = tid;
    float acc = embedding[zc * D + c];
    for (int e = 0; e < D; e += 4) {
      const float4 g4 = *(const float4*)&s_agg[e];
      acc = fmaf(g4.x, Wo[(e + 0) * D + c], acc);
      acc = fmaf(g4.y, Wo[(e + 1) * D + c], acc);
      acc = fmaf(g4.z, Wo[(e + 2) * D + c], acc);
      acc = fmaf(g4.w, Wo[(e + 3) * D + c], acc);
    }
    out[a * D + c] = acc;
  }
}

// ===========================================================================
extern "C" void kernel_launch(void* const* d_in, const int* in_sizes, int n_in,
                              void* d_out, int out_size, void* d_ws, size_t ws_size,
                              hipStream_t stream) {
  const float* positions = (const float*)d_in[0];
  const int*   z         = (const int*)d_in[1];
  const int*   neighbors = (const int*)d_in[2];
  const float* nmask     = (const float*)d_in[3];
  const float* embedding = (const float*)d_in[4];
  const float* filt_W    = (const float*)d_in[5];
  const float* filt_b    = (const float*)d_in[6];
  const float* Wq        = (const float*)d_in[7];
  const float* Wk        = (const float*)d_in[8];
  const float* Wv        = (const float*)d_in[9];
  const float* Wo        = (const float*)d_in[10];
  float* out = (float*)d_out;
  const int natoms = in_sizes[1];  // 8192

  if (ws_size >= WS_NEED) {
    char* ws = (char*)d_ws;
    _Float16* P    = (_Float16*)(ws + WS_P);
    _Float16* QKz  = (_Float16*)(ws + WS_QKZ);
    _Float16* WvoT = (_Float16*)(ws + WS_WVOT);
    float*    qz   = (float*)(ws + WS_QZ);
    _Float16* fWTP = (_Float16*)(ws + WS_FWTP);
    _Float16* embh = (_Float16*)(ws + WS_EMBH);
    k0a_qz<<<50, NTHREADS, 0, stream>>>(embedding, Wq, qz);
    k0b_prep<<<964, NTHREADS, 0, stream>>>(filt_W, Wk, Wv, Wo, qz, embedding,
                                           QKz, WvoT, fWTP, embh);
    k2_attn<<<natoms, NTHREADS, 0, stream>>>(positions, z, neighbors, nmask,
                                             embh, filt_b, fWTP, QKz, P);
    k3_gemm<<<natoms / 16 * 2, NTHREADS, 0, stream>>>(z, embedding, P, WvoT, out);
  } else {
    tdt_mono<<<natoms, NTHREADS, 0, stream>>>(positions, z, neighbors, nmask,
                                              embedding, filt_W, filt_b,
                                              Wq, Wk, Wv, Wo, out);
  }
}